// Round 1
// baseline (154.499 us; speedup 1.0000x reference)
//
#include <hip/hip_runtime.h>

#define G_ 100
#define T_ 24
#define GP1 101
#define TILE (G_ * T_)        // 2400 floats per (b,pass) tile
#define VPB (TILE / 4)        // 600 float4 per tile
#define WPB 4                 // waves per block: 2 b's x 2 passes
#define BLOCK (64 * WPB)

typedef float vfloat4 __attribute__((ext_vector_type(4)));

// Merit-order chunk: batch N scattered 96B-row cap loads from global,
// serial clip-scan, allocs written to the wave-private LDS tile column.
// ord/price come from per-wave registers via v_readlane (uniform -> SGPR,
// ignores exec mask so it is safe inside the lane<24 divergent branch).
template<int N>
__device__ __forceinline__ void scan_chunk(int k0,
    const float* __restrict__ capp,          // R_p[b] + t (per-lane)
    int ord_lo, int ord_hi, float pr_lo, float pr_hi,
    float* __restrict__ ldscol,              // tw + t
    float dem, float& before, float& objp)
{
    int gg[N]; float pr[N], cap[N];
#pragma unroll
    for (int j = 0; j < N; ++j) {
        const int idx = k0 + j;              // compile-time constant
        if (idx < 64) {
            gg[j] = __builtin_amdgcn_readlane(ord_lo, idx);
            pr[j] = __int_as_float(__builtin_amdgcn_readlane(__float_as_int(pr_lo), idx));
        } else {
            gg[j] = __builtin_amdgcn_readlane(ord_hi, idx - 64);
            pr[j] = __int_as_float(__builtin_amdgcn_readlane(__float_as_int(pr_hi), idx - 64));
        }
    }
#pragma unroll
    for (int j = 0; j < N; ++j) cap[j] = capp[gg[j] * T_];   // N loads in flight
#pragma unroll
    for (int j = 0; j < N; ++j) {
        float a = fminf(fmaxf(dem - before, 0.f), cap[j]);
        before += cap[j];
        objp = fmaf(pr[j], a, objp);
        ldscol[gg[j] * T_] = a;              // ds_write, own column
    }
}

__global__ __launch_bounds__(BLOCK, 4) void dispatch_kernel(
    const float* __restrict__ R_up, const float* __restrict__ R_dn,
    const float* __restrict__ omega,
    const float* __restrict__ b_G, const float* __restrict__ voll,
    const float* __restrict__ vosp, const float* __restrict__ ru,
    const float* __restrict__ rd,
    float* __restrict__ out, int B)
{
    __shared__ float s_tile[WPB * TILE];     // 38400 B -> 4 blocks/CU, 16 tiles
    __shared__ float s_obj[WPB];

    const int tid  = threadIdx.x;

    // ---- fused in-block merit-order sort (== stable jnp.argsort of prices).
    // Scratch lives in wave0's tile region; wiped by the zeroing pass below.
    //   raw prices:  floats [0,101) up, [128,229) dn
    //   sorted ord:  ints   [256+p*128 + r]
    //   sorted pr:   floats [512+p*128 + r]
    if (tid < GP1) {
        float mu, md;
        if (tid < G_) { float bg = b_G[tid]; mu = ru[0] * bg; md = rd[0] * bg; }
        else          { mu = voll[0];        md = vosp[0]; }
        s_tile[tid] = mu; s_tile[128 + tid] = md;
    }
    __syncthreads();
    if (tid < GP1) {
        const float mu = s_tile[tid], md = s_tile[128 + tid];
        int r0 = 0, r1 = 0;
        for (int j = 0; j < GP1; ++j) {
            float vu = s_tile[j], vd = s_tile[128 + j];
            r0 += (vu < mu) || (vu == mu && j < tid);
            r1 += (vd < md) || (vd == md && j < tid);
        }
        ((int*)s_tile)[256 + r0] = tid;  s_tile[512 + r0] = mu;
        ((int*)s_tile)[384 + r1] = tid;  s_tile[640 + r1] = md;
    }
    __syncthreads();

    const int w    = tid >> 6;
    const int lane = tid & 63;
    const int b = __builtin_amdgcn_readfirstlane(blockIdx.x * 2 + (w >> 1));
    const int p = __builtin_amdgcn_readfirstlane(w & 1);
    const size_t bgt = (size_t)B * TILE;
    float* __restrict__ tw = &s_tile[w * TILE];   // wave-private tile

    // cache this wave's sorted merit order in registers (lane r holds rank r,
    // lane r holds rank 64+r in the _hi pair; only ranks 64..100 exist there)
    const int hi_ok = (lane < GP1 - 64);
    const int   ord_lo = ((const int*)s_tile)[256 + p * 128 + lane];
    const int   ord_hi = hi_ok ? ((const int*)s_tile)[256 + p * 128 + 64 + lane] : 0;
    const float pr_lo  = s_tile[512 + p * 128 + lane];
    const float pr_hi  = hi_ok ? s_tile[512 + p * 128 + 64 + lane] : 0.f;
    __syncthreads();                          // scratch reads done before zeroing

    // ---- zero the LDS tile: untouched merit rows must be exactly 0 ----
#pragma unroll
    for (int j = 0; j < 9; ++j) *(vfloat4*)&tw[(lane + j * 64) * 4] = (vfloat4)(0.f);
    if (lane < VPB - 576)       *(vfloat4*)&tw[(lane + 576) * 4]    = (vfloat4)(0.f);

    const int t = (lane < T_) ? lane : 0;    // scan lanes: 0..23

    float objp = 0.f;
    if (lane < T_) {
        const float om  = omega[(size_t)b * T_ + t];
        const float dem = p ? fmaxf(-om, 0.f) : fmaxf(om, 0.f);
        const float* __restrict__ capp = (p ? R_dn : R_up) + (size_t)b * TILE + t;
        float* __restrict__ ldscol = tw + t;

        float before = 0.f;
        // front-loaded 16-wide chunks cover typical k* (~25-35) in 2 windows;
        // 8-wide ballot chunks catch the tail; slack handled analytically.
        scan_chunk<16>( 0, capp, ord_lo, ord_hi, pr_lo, pr_hi, ldscol, dem, before, objp);
        bool run = __any(before < dem);
        if (run) { scan_chunk<16>(16, capp, ord_lo, ord_hi, pr_lo, pr_hi, ldscol, dem, before, objp);
                   run = __any(before < dem); }
        if (run) { scan_chunk< 8>(32, capp, ord_lo, ord_hi, pr_lo, pr_hi, ldscol, dem, before, objp);
                   run = __any(before < dem); }
        if (run) { scan_chunk< 8>(40, capp, ord_lo, ord_hi, pr_lo, pr_hi, ldscol, dem, before, objp);
                   run = __any(before < dem); }
        if (run) { scan_chunk< 8>(48, capp, ord_lo, ord_hi, pr_lo, pr_hi, ldscol, dem, before, objp);
                   run = __any(before < dem); }
        if (run) { scan_chunk< 8>(56, capp, ord_lo, ord_hi, pr_lo, pr_hi, ldscol, dem, before, objp);
                   run = __any(before < dem); }
        if (run) { scan_chunk< 8>(64, capp, ord_lo, ord_hi, pr_lo, pr_hi, ldscol, dem, before, objp);
                   run = __any(before < dem); }
        if (run) { scan_chunk< 8>(72, capp, ord_lo, ord_hi, pr_lo, pr_hi, ldscol, dem, before, objp);
                   run = __any(before < dem); }
        if (run) { scan_chunk< 8>(80, capp, ord_lo, ord_hi, pr_lo, pr_hi, ldscol, dem, before, objp);
                   run = __any(before < dem); }
        if (run) { scan_chunk< 8>(88, capp, ord_lo, ord_hi, pr_lo, pr_hi, ldscol, dem, before, objp);
                   run = __any(before < dem); }
        if (run)   scan_chunk< 4>(96, capp, ord_lo, ord_hi, pr_lo, pr_hi, ldscol, dem, before, objp);

        // slack (rank 100 == GP1-1): clip(dem - sum_all, 0, dem); early exit => 0.
        const float slack_pr =
            __int_as_float(__builtin_amdgcn_readlane(__float_as_int(pr_hi), GP1 - 1 - 64));
        float slackv = fmaxf(dem - before, 0.f);
        objp = fmaf(slack_pr, slackv, objp);
        out[2 * bgt + (size_t)p * B * T_ + (size_t)b * T_ + t] = slackv;
    }

    // ---- rt_obj partial: butterfly over the wave (idle lanes hold 0) ----
#pragma unroll
    for (int off = 32; off; off >>= 1) objp += __shfl_xor(objp, off, 64);
    if (lane == 0) s_obj[w] = objp;

    // ---- stream the finished tile out: coalesced plain float4 (6.6 TB/s path)
    __builtin_amdgcn_wave_barrier();         // pin ds_write -> ds_read order
    {
        vfloat4* __restrict__ dst = (vfloat4*)out + ((size_t)p * B + b) * VPB;
#pragma unroll
        for (int j = 0; j < 9; ++j)
            dst[lane + j * 64] = *(const vfloat4*)&tw[(lane + j * 64) * 4];
        if (lane < VPB - 576)
            dst[lane + 576] = *(const vfloat4*)&tw[(lane + 576) * 4];
    }

    // ---- pair up+dn partials per b (barrier hides under stream-out) ----
    __syncthreads();
    if (tid == 0)
        out[2 * bgt + 2 * (size_t)B * T_ + b] = s_obj[0] + s_obj[1];
    if (tid == 128)
        out[2 * bgt + 2 * (size_t)B * T_ + b] = s_obj[2] + s_obj[3];
}

extern "C" void kernel_launch(void* const* d_in, const int* in_sizes, int n_in,
                              void* d_out, int out_size, void* d_ws, size_t ws_size,
                              hipStream_t stream)
{
    const float* R_up  = (const float*)d_in[0];
    const float* R_dn  = (const float*)d_in[1];
    const float* omega = (const float*)d_in[2];
    const float* b_G   = (const float*)d_in[3];
    const float* voll  = (const float*)d_in[4];
    const float* vosp  = (const float*)d_in[5];
    const float* ru    = (const float*)d_in[6];
    const float* rd    = (const float*)d_in[7];

    const int B = in_sizes[0] / TILE;
    float* out = (float*)d_out;

    // single fused launch: 4 waves/block = 2 b's x 2 passes; grid B/2
    dispatch_kernel<<<B / 2, BLOCK, 0, stream>>>(
        R_up, R_dn, omega, b_G, voll, vosp, ru, rd, out, B);
}

// Round 2
// 152.822 us; speedup vs baseline: 1.0110x; 1.0110x over previous
//
#include <hip/hip_runtime.h>

#define G_ 100
#define T_ 24
#define GP1 101
#define TILE (G_ * T_)        // 2400 floats per (b,pass) tile
#define VPB (TILE / 4)        // 600 float4 per tile
#define BPB 4                 // b's per block
#define WPB (BPB * 2)         // 8 waves: 4 b's x 2 passes
#define BLOCK (64 * WPB)      // 512 threads

typedef float vfloat4 __attribute__((ext_vector_type(4)));

// Merit-order chunk: batch N scattered 96B-row cap loads from global,
// serial clip-scan, allocs stored DIRECTLY to the global output tile
// (lines are L2-present from the preceding zero pass, so the 96B partial
// writes merge in L2 without RFO). ord/price come from per-wave registers
// via v_readlane (uniform -> SGPR, exec-mask-ignoring, safe under lane<24).
template<int N>
__device__ __forceinline__ void scan_chunk(int k0,
    const float* __restrict__ capp,          // R_p[b] + t (per-lane)
    float* __restrict__ gcol,                // out tile + t (per-lane)
    int ord_lo, int ord_hi, float pr_lo, float pr_hi,
    float dem, float& before, float& objp)
{
    int gg[N]; float pr[N], cap[N];
#pragma unroll
    for (int j = 0; j < N; ++j) {
        const int idx = k0 + j;              // compile-time constant
        if (idx < 64) {
            gg[j] = __builtin_amdgcn_readlane(ord_lo, idx);
            pr[j] = __int_as_float(__builtin_amdgcn_readlane(__float_as_int(pr_lo), idx));
        } else {
            gg[j] = __builtin_amdgcn_readlane(ord_hi, idx - 64);
            pr[j] = __int_as_float(__builtin_amdgcn_readlane(__float_as_int(pr_hi), idx - 64));
        }
    }
#pragma unroll
    for (int j = 0; j < N; ++j) cap[j] = capp[gg[j] * T_];   // N loads in flight
#pragma unroll
    for (int j = 0; j < N; ++j) {
        float a = fminf(fmaxf(dem - before, 0.f), cap[j]);
        before += cap[j];
        objp = fmaf(pr[j], a, objp);
        gcol[gg[j] * T_] = a;                // direct global store, own column
    }
}

__global__ __launch_bounds__(BLOCK, 8) void dispatch_kernel(
    const float* __restrict__ R_up, const float* __restrict__ R_dn,
    const float* __restrict__ omega,
    const float* __restrict__ b_G, const float* __restrict__ voll,
    const float* __restrict__ vosp, const float* __restrict__ ru,
    const float* __restrict__ rd,
    float* __restrict__ out, int B)
{
    // tiny LDS only: sort scratch + obj pairing -> occupancy is wave-limited
    __shared__ float s_praw[2][GP1];
    __shared__ int   s_ord [2][128];
    __shared__ float s_pr  [2][128];
    __shared__ float s_obj [WPB];

    const int tid = threadIdx.x;

    // ---- fused merit-order sort (== stable jnp.argsort of prices) ----
    if (tid < GP1) {
        float mu, md;
        if (tid < G_) { float bg = b_G[tid]; mu = ru[0] * bg; md = rd[0] * bg; }
        else          { mu = voll[0];        md = vosp[0]; }
        s_praw[0][tid] = mu; s_praw[1][tid] = md;
    }
    __syncthreads();
    {   // up-ranks on threads [0,101), dn-ranks on threads [256,357) (parallel waves)
        const int pass = tid >> 8;
        const int i    = tid & 255;
        if (i < GP1) {
            const float m = s_praw[pass][i];
            int r = 0;
            for (int j = 0; j < GP1; ++j) {
                const float v = s_praw[pass][j];
                r += (v < m) || (v == m && j < i);
            }
            s_ord[pass][r] = i;  s_pr[pass][r] = m;
        }
    }
    __syncthreads();

    const int w    = tid >> 6;
    const int lane = tid & 63;
    const int b = __builtin_amdgcn_readfirstlane(blockIdx.x * BPB + (w >> 1));
    const int p = __builtin_amdgcn_readfirstlane(w & 1);
    const size_t bgt = (size_t)B * TILE;

    // cache this wave's sorted merit order in registers
    const int hi_ok = (lane < GP1 - 64);
    const int   ord_lo = s_ord[p][lane];
    const int   ord_hi = hi_ok ? s_ord[p][64 + lane] : 0;
    const float pr_lo  = s_pr [p][lane];
    const float pr_hi  = hi_ok ? s_pr [p][64 + lane] : 0.f;

    // ---- zero the whole output tile, coalesced float4 from registers ----
    {
        vfloat4* __restrict__ dst = (vfloat4*)out + ((size_t)p * B + b) * VPB;
#pragma unroll
        for (int j = 0; j < 9; ++j) dst[lane + j * 64] = (vfloat4)(0.f);
        if (lane < VPB - 576)       dst[lane + 576]    = (vfloat4)(0.f);
    }
    // order zero-stores before the scan's overwrites (stores complete OOO
    // without this; memory clobber also pins compiler ordering)
    asm volatile("s_waitcnt vmcnt(0)" ::: "memory");

    const int t = (lane < T_) ? lane : 0;    // scan lanes: 0..23

    float objp = 0.f;
    if (lane < T_) {
        const float om  = omega[(size_t)b * T_ + t];
        const float dem = p ? fmaxf(-om, 0.f) : fmaxf(om, 0.f);
        const float* __restrict__ capp = (p ? R_dn : R_up) + (size_t)b * TILE + t;
        float* __restrict__ gcol = out + (size_t)p * bgt + (size_t)b * TILE + t;

        float before = 0.f;
        // front-loaded 16-wide chunks cover typical k* (~25-35) in 2 windows;
        // 8-wide ballot chunks catch the tail; slack handled analytically.
        scan_chunk<16>( 0, capp, gcol, ord_lo, ord_hi, pr_lo, pr_hi, dem, before, objp);
        bool run = __any(before < dem);
        if (run) { scan_chunk<16>(16, capp, gcol, ord_lo, ord_hi, pr_lo, pr_hi, dem, before, objp);
                   run = __any(before < dem); }
        if (run) { scan_chunk< 8>(32, capp, gcol, ord_lo, ord_hi, pr_lo, pr_hi, dem, before, objp);
                   run = __any(before < dem); }
        if (run) { scan_chunk< 8>(40, capp, gcol, ord_lo, ord_hi, pr_lo, pr_hi, dem, before, objp);
                   run = __any(before < dem); }
        if (run) { scan_chunk< 8>(48, capp, gcol, ord_lo, ord_hi, pr_lo, pr_hi, dem, before, objp);
                   run = __any(before < dem); }
        if (run) { scan_chunk< 8>(56, capp, gcol, ord_lo, ord_hi, pr_lo, pr_hi, dem, before, objp);
                   run = __any(before < dem); }
        if (run) { scan_chunk< 8>(64, capp, gcol, ord_lo, ord_hi, pr_lo, pr_hi, dem, before, objp);
                   run = __any(before < dem); }
        if (run) { scan_chunk< 8>(72, capp, gcol, ord_lo, ord_hi, pr_lo, pr_hi, dem, before, objp);
                   run = __any(before < dem); }
        if (run) { scan_chunk< 8>(80, capp, gcol, ord_lo, ord_hi, pr_lo, pr_hi, dem, before, objp);
                   run = __any(before < dem); }
        if (run) { scan_chunk< 8>(88, capp, gcol, ord_lo, ord_hi, pr_lo, pr_hi, dem, before, objp);
                   run = __any(before < dem); }
        if (run)   scan_chunk< 4>(96, capp, gcol, ord_lo, ord_hi, pr_lo, pr_hi, dem, before, objp);

        // slack (rank 100 == GP1-1): clip(dem - sum_all, 0, dem); early exit => 0.
        const float slack_pr =
            __int_as_float(__builtin_amdgcn_readlane(__float_as_int(pr_hi), GP1 - 1 - 64));
        float slackv = fmaxf(dem - before, 0.f);
        objp = fmaf(slack_pr, slackv, objp);
        out[2 * bgt + (size_t)p * B * T_ + (size_t)b * T_ + t] = slackv;
    }

    // ---- rt_obj partial: butterfly over the wave (idle lanes hold 0) ----
#pragma unroll
    for (int off = 32; off; off >>= 1) objp += __shfl_xor(objp, off, 64);
    if (lane == 0) s_obj[w] = objp;

    // ---- pair up+dn partials per b ----
    __syncthreads();
    if ((tid & 127) == 0)
        out[2 * bgt + 2 * (size_t)B * T_ + b] = s_obj[w] + s_obj[w + 1];
}

extern "C" void kernel_launch(void* const* d_in, const int* in_sizes, int n_in,
                              void* d_out, int out_size, void* d_ws, size_t ws_size,
                              hipStream_t stream)
{
    const float* R_up  = (const float*)d_in[0];
    const float* R_dn  = (const float*)d_in[1];
    const float* omega = (const float*)d_in[2];
    const float* b_G   = (const float*)d_in[3];
    const float* voll  = (const float*)d_in[4];
    const float* vosp  = (const float*)d_in[5];
    const float* ru    = (const float*)d_in[6];
    const float* rd    = (const float*)d_in[7];

    const int B = in_sizes[0] / TILE;
    float* out = (float*)d_out;

    // single fused launch: 8 waves/block = 4 b's x 2 passes; grid B/4
    dispatch_kernel<<<B / BPB, BLOCK, 0, stream>>>(
        R_up, R_dn, omega, b_G, voll, vosp, ru, rd, out, B);
}